// Round 4
// baseline (1690.072 us; speedup 1.0000x reference)
//
#include <hip/hip_runtime.h>

// WindowAttention: B_=4096, N=49, C=384, H=12, hd=32, nW=1024
// R2 source, third submission (two prior MI355X container failures with no
// compile/verify verdict; source audited twice — no hang path, no OOB, all
// barriers uniform, duplicate stores bit-identical).
//     (a) in-accumulator softmax (Ss deleted, all 4 waves), (b) rel-pos bias
//     precomputed to a [12][49][49] f32 table in ws (Rpb LDS deleted),
//     (c) fragment-major LDS layouts ([kchunk][row][8], 16B rows, dense b128),
//     (d) PV result stored directly to global via shfl column-pair packing
//     (O->LDS->global stage deleted). attn LDS 76288 -> 54272 B = 3 blocks/CU,
//     barriers 5/head -> 3/head.
//     proj: 32-token blocks, LDS 25088 B -> 6 blocks/CU, grid 6272.

#define SCALE_Q 0.17677669529663687f

typedef __bf16 bf16x8 __attribute__((ext_vector_type(8)));
typedef float f32x4 __attribute__((ext_vector_type(4)));

__device__ __forceinline__ unsigned short f2bf(float f) {
  union { float f; unsigned int u; } c; c.f = f;
  unsigned int u = c.u;
  return (unsigned short)((u + 0x7FFFu + ((u >> 16) & 1u)) >> 16);
}

__device__ __forceinline__ f32x4 mfma16(bf16x8 a, bf16x8 b, f32x4 c) {
  return __builtin_amdgcn_mfma_f32_16x16x32_bf16(a, b, c, 0, 0, 0);
}

// fallback path: build a bf16x8 B-fragment from 8 consecutive f32
__device__ __forceinline__ bf16x8 cvt8_frag(const float* __restrict__ src) {
  const float4 a = *(const float4*)src;
  const float4 b = *(const float4*)(src + 4);
  union { bf16x8 v; unsigned short u[8]; } c;
  c.u[0] = f2bf(a.x); c.u[1] = f2bf(a.y); c.u[2] = f2bf(a.z); c.u[3] = f2bf(a.w);
  c.u[4] = f2bf(b.x); c.u[5] = f2bf(b.y); c.u[6] = f2bf(b.z); c.u[7] = f2bf(b.w);
  return c.v;
}

// ws layout (ushort base):
//   [0, 442368)        qkv fragments  (864 frags x 64 lanes x 8 bf16)
//   [442368, 589824)   proj fragments (288 frags x 64 lanes x 8 bf16)
//   byte 1179648...    f32 bias table [12][49][49] (28812 floats)
__global__ void conv_w_kernel(const float* __restrict__ qkv_w,
                              const float* __restrict__ proj_w,
                              const float* __restrict__ rpb,
                              unsigned short* __restrict__ wbf) {
  const int f = blockIdx.x * 256 + threadIdx.x;
  const int lane = f & 63;
  const int l15 = lane & 15;
  const int quad = (lane >> 4) & 3;
  const float* src;
  unsigned short* dst;
  if (f < 55296) {
    const int rest = f >> 6;
    const int kk = rest % 12;
    const int ht = rest / 12;
    const int t = ht % 6, h = ht / 6;
    const int n96 = t * 16 + l15;
    const int grow = (n96 >> 5) * 384 + h * 32 + (n96 & 31);
    src = qkv_w + (size_t)grow * 384 + kk * 32 + quad * 8;
    dst = wbf + (size_t)f * 8;
  } else if (f < 73728) {
    const int p = f - 55296;
    const int rest = p >> 6;
    const int kk = rest % 12, t = rest / 12;
    src = proj_w + (size_t)(t * 16 + l15) * 384 + kk * 32 + quad * 8;
    dst = wbf + 442368 + (size_t)p * 8;
  } else if (f < 73728 + 28812) {
    // precompute bias[h][i][j] = rpb[rel(i,j)*12 + h]
    const int t = f - 73728;
    const int h = t / 2401, ij = t - h * 2401;
    const int i = ij / 49, j = ij - (ij / 49) * 49;
    const int ri = i / 7, ci = i - ri * 7;
    const int rj = j / 7, cj = j - rj * 7;
    const int rel = (ri - rj + 6) * 13 + (ci - cj + 6);
    ((float*)(wbf + 589824))[t] = rpb[rel * 12 + h];
    return;
  } else {
    return;
  }
  const float4 a = *(const float4*)src;
  const float4 b = *(const float4*)(src + 4);
  ushort4 s0, s1;
  s0.x = f2bf(a.x); s0.y = f2bf(a.y); s0.z = f2bf(a.z); s0.w = f2bf(a.w);
  s1.x = f2bf(b.x); s1.y = f2bf(b.y); s1.z = f2bf(b.z); s1.w = f2bf(b.w);
  *(ushort4*)dst = s0;
  *(ushort4*)(dst + 4) = s1;
}

template <bool PRECONV>
__global__ __launch_bounds__(256, 3)
void attn_kernel(const float* __restrict__ x, const float* __restrict__ mask,
                 const float* __restrict__ qkv_w, const float* __restrict__ qkv_b,
                 const float* __restrict__ rpb, const float* __restrict__ lamb,
                 const unsigned short* __restrict__ qkv_w_bf,
                 const float* __restrict__ biasws,
                 float* __restrict__ out) {
  // Fragment-major LDS: [k-chunk][row][8 bf16] -> each frag row is one 16B
  // aligned unit; wave b128 reads are dense (16 lanes x contiguous 16B).
  __shared__ __align__(16) unsigned short Xs[48][49][8];  // x window (K=384)
  __shared__ __align__(16) unsigned short Qs[4][49][8];   // q*scale (K=32)
  __shared__ __align__(16) unsigned short Ks[4][49][8];   // k       (K=32)
  __shared__ __align__(16) unsigned short Vt[8][32][8];   // v^T [j-chunk][d][8]
  __shared__ __align__(16) unsigned short Pb[8][49][8];   // P    (K=64)
  // total: 37632+3136+3136+4096+6272 = 54272 B -> 3 blocks/CU

  const int tid  = threadIdx.x;
  const int b    = blockIdx.x;
  const int lane = tid & 63;
  const int wv   = tid >> 6;        // 0..3
  const int l15  = lane & 15;
  const int quad = lane >> 4;       // 0..3

  // ---- stage x window (fp32 -> bf16, fragment-major), zero pad planes ----
  {
    const float* xw = x + (size_t)b * (49 * 384);
    for (int t = tid; t < 49 * 48; t += 256) {
      int row = t / 48, c = t - row * 48;
      const float4 v0 = *(const float4*)(xw + row * 384 + c * 8);
      const float4 v1 = *(const float4*)(xw + row * 384 + c * 8 + 4);
      union { unsigned short u[8]; uint4 v; } s;
      s.u[0] = f2bf(v0.x); s.u[1] = f2bf(v0.y); s.u[2] = f2bf(v0.z); s.u[3] = f2bf(v0.w);
      s.u[4] = f2bf(v1.x); s.u[5] = f2bf(v1.y); s.u[6] = f2bf(v1.z); s.u[7] = f2bf(v1.w);
      *(uint4*)&Xs[c][row][0] = s.v;
    }
    // zero j-pad planes of Vt (j=49..63) and Pb (cols 49..63); j=48 plane
    // entries are rewritten every head before use.
    unsigned int* vz = (unsigned int*)&Vt[6][0][0];
    if (tid < 256) vz[tid] = 0;                       // 512 ushorts
    unsigned int* pz = (unsigned int*)&Pb[6][0][0];
    for (int t = tid; t < 392; t += 256) pz[t] = 0;   // 784 ushorts
  }

  const float* mbase = mask + (size_t)(b & 1023) * (49 * 49);

  // per-wave output-row tile for S/softmax/PV/store phases
  const int m0s = (wv * 16 > 33) ? 33 : wv * 16;      // {0,16,32,33}

  // mask values are (row,col)-fixed per lane across all heads -> registers
  float mk[4][4];
#pragma unroll
  for (int r = 0; r < 4; ++r) {
#pragma unroll
    for (int nt = 0; nt < 4; ++nt) {
      const int row = m0s + quad * 4 + r;
      const int col = ((nt * 16 > 33) ? 33 : nt * 16) + l15;
      mk[r][nt] = mbase[row * 49 + col];
    }
  }
  __syncthreads();

  for (int h = 0; h < 12; ++h) {
    // ---- qkv GEMM MFMA loop: M=49 (tiles 0,16,32,33), N=96, K=384.
    //      Reads Xs (stable) + global W frags only -> runs before the
    //      barrier, overlapping other waves' tail of the previous head. ----
    const int mp = wv >> 1, g = wv & 1;
    const int m0a = mp * 32;            // 0 or 32
    const int m0b = mp ? 33 : 16;       // 16 or 33
    f32x4 acc[2][3] = {};
    {
      const unsigned short* wg =
          qkv_w_bf + ((size_t)(h * 6 + g * 3) * 12) * 512 + lane * 8;
      for (int kk = 0; kk < 12; ++kk) {
        const bf16x8 a0 = *(const bf16x8*)&Xs[kk * 4 + quad][m0a + l15][0];
        const bf16x8 a1 = *(const bf16x8*)&Xs[kk * 4 + quad][m0b + l15][0];
#pragma unroll
        for (int e = 0; e < 3; ++e) {
          bf16x8 bb;
          if (PRECONV) {
            bb = *(const bf16x8*)(wg + (e * 12 + kk) * 512);
          } else {
            const int n96 = (g * 3 + e) * 16 + l15;
            const int grow = (n96 >> 5) * 384 + h * 32 + (n96 & 31);
            bb = cvt8_frag(qkv_w + (size_t)grow * 384 + kk * 32 + quad * 8);
          }
          acc[0][e] = mfma16(a0, bb, acc[0][e]);
          acc[1][e] = mfma16(a1, bb, acc[1][e]);
        }
      }
    }
    __syncthreads();   // prev head's S reads (Qs,Ks) and PV reads (Pb,Vt) done

    // ---- epilogue: scatter q,k,v into fragment-major LDS ----
#pragma unroll
    for (int im = 0; im < 2; ++im) {
      const int m0 = im ? m0b : m0a;
#pragma unroll
      for (int e = 0; e < 3; ++e) {
        const int n96 = (g * 3 + e) * 16 + l15;
        const int sub = n96 >> 5, c32 = n96 & 31;
        const float bias = qkv_b[sub * 384 + h * 32 + c32];
#pragma unroll
        for (int r = 0; r < 4; ++r) {
          const int row = m0 + quad * 4 + r;   // <= 48 always
          const float val = acc[im][e][r] + bias;
          if (sub == 0)      Qs[c32 >> 3][row][c32 & 7] = f2bf(val * SCALE_Q);
          else if (sub == 1) Ks[c32 >> 3][row][c32 & 7] = f2bf(val);
          else               Vt[row >> 3][c32][row & 7] = f2bf(val);
        }
      }
    }
    __syncthreads();

    // ---- S = q k^T (K=32) + in-accumulator softmax -> Pb ----
    {
      const bf16x8 aq = *(const bf16x8*)&Qs[quad][m0s + l15][0];
      f32x4 sacc[4];
#pragma unroll
      for (int nt = 0; nt < 4; ++nt) {
        const int n0 = (nt * 16 > 33) ? 33 : nt * 16;
        const bf16x8 bk = *(const bf16x8*)&Ks[quad][n0 + l15][0];
        f32x4 z = {0.f, 0.f, 0.f, 0.f};
        sacc[nt] = mfma16(aq, bk, z);
      }
      // softmax over rows m0s+quad*4+r; cols (nt,l15) cover 0..48 with
      // cols 33..47 duplicated between nt=2 and nt=3 (dedup in the sum).
      const float lam = lamb[h];
      const float sc = 1.f + lam;
      const float ad = -lam * (1.0f / 49.0f);
      const float* bh = biasws + h * 2401;
#pragma unroll
      for (int r = 0; r < 4; ++r) {
        const int row = m0s + quad * 4 + r;
        float val[4];
#pragma unroll
        for (int nt = 0; nt < 4; ++nt) {
          const int col = ((nt * 16 > 33) ? 33 : nt * 16) + l15;
          float bm;
          if (PRECONV) {
            bm = bh[row * 49 + col];
          } else {
            const int ri = (row * 37) >> 8, ci = row - ri * 7;
            const int rj = (col * 37) >> 8, cj = col - rj * 7;
            bm = rpb[((ri - rj + 6) * 13 + (ci - cj + 6)) * 12 + h];
          }
          val[nt] = sacc[nt][r] + bm + mk[r][nt];
        }
        float mx = fmaxf(fmaxf(val[0], val[1]), fmaxf(val[2], val[3]));
        mx = fmaxf(mx, __shfl_xor(mx, 1));
        mx = fmaxf(mx, __shfl_xor(mx, 2));
        mx = fmaxf(mx, __shfl_xor(mx, 4));
        mx = fmaxf(mx, __shfl_xor(mx, 8));
        const float e0 = __expf(val[0] - mx);
        const float e1 = __expf(val[1] - mx);
        const float e2 = __expf(val[2] - mx);
        const float e3 = __expf(val[3] - mx);
        float s = e0 + e1 + e2 + ((l15 == 15) ? e3 : 0.f);
        s += __shfl_xor(s, 1);
        s += __shfl_xor(s, 2);
        s += __shfl_xor(s, 4);
        s += __shfl_xor(s, 8);
        const float se = sc / s;
        const int c0 = l15, c1 = 16 + l15, c2 = 32 + l15, c3 = 33 + l15;
        Pb[c0 >> 3][row][c0 & 7] = f2bf(e0 * se + ad);
        Pb[c1 >> 3][row][c1 & 7] = f2bf(e1 * se + ad);
        Pb[c2 >> 3][row][c2 & 7] = f2bf(e2 * se + ad);
        Pb[c3 >> 3][row][c3 & 7] = f2bf(e3 * se + ad);
      }
    }
    __syncthreads();

    // ---- O = P V (K=64) + direct coalesced store ----
    {
      f32x4 oacc[2] = {};
#pragma unroll
      for (int kk = 0; kk < 2; ++kk) {
        const bf16x8 ap = *(const bf16x8*)&Pb[kk * 4 + quad][m0s + l15][0];
#pragma unroll
        for (int nt = 0; nt < 2; ++nt) {
          const bf16x8 bv = *(const bf16x8*)&Vt[kk * 4 + quad][nt * 16 + l15][0];
          oacc[nt] = mfma16(ap, bv, oacc[nt]);
        }
      }
      // lane l15 stores col pair (2*l15, 2*l15+1): one uint per row, 64B
      // per 16-lane group. Rows 33..47 stored twice (identical bytes).
      const int s0 = (quad << 4) | ((l15 & 7) << 1);
#pragma unroll
      for (int r = 0; r < 4; ++r) {
        const float x00 = __shfl(oacc[0][r], s0);
        const float x01 = __shfl(oacc[0][r], s0 + 1);
        const float x10 = __shfl(oacc[1][r], s0);
        const float x11 = __shfl(oacc[1][r], s0 + 1);
        const float lo = (l15 < 8) ? x00 : x10;
        const float hi = (l15 < 8) ? x01 : x11;
        const unsigned int w =
            ((unsigned int)f2bf(hi) << 16) | (unsigned int)f2bf(lo);
        const int row = m0s + quad * 4 + r;
        *(unsigned int*)((char*)out +
            (size_t)(b * 49 + row) * 1536 + h * 64 + l15 * 4) = w;
      }
    }
    // no barrier here: next head's MFMA loop touches only Xs + global
  }
}

template <bool PRECONV>
__global__ __launch_bounds__(256, 6)
void proj_kernel(const float* __restrict__ proj_w, const float* __restrict__ proj_b,
                 const unsigned short* __restrict__ proj_w_bf,
                 float* __restrict__ out) {
  // 32 tokens/block, LDS 25088 B -> 6 blocks/CU; barrier-free main loop.
  __shared__ __align__(16) unsigned short Ains[32][392];
  const int tid  = threadIdx.x;
  const int mb   = blockIdx.x;           // 6272 blocks x 32 tokens
  const int lane = tid & 63;
  const int wv   = tid >> 6;
  const int l15  = lane & 15;
  const int quad = lane >> 4;

  // stage this block's 32 token rows (bf16, first 768B of each slot)
  for (int t = tid; t < 32 * 48; t += 256) {
    int row = t / 48, ch = t - row * 48;
    const uint4 v = *(const uint4*)((const char*)out +
        (size_t)(mb * 32 + row) * 1536 + ch * 16);
    *(uint4*)&Ains[row][ch * 8] = v;
  }
  __syncthreads();   // after this, in-place overwrite of our slots is safe

  const int mp = wv >> 1, np = wv & 1;
  const unsigned short* pw = proj_w_bf + lane * 8;

  for (int nc = 0; nc < 6; ++nc) {
    const int t0 = nc * 4 + np * 2;      // packed n-tile index (t0, t0+1)
    f32x4 acc[2] = {};
    for (int kk = 0; kk < 12; ++kk) {
      const int k0 = kk * 32 + quad * 8;
      const bf16x8 a = *(const bf16x8*)&Ains[mp * 16 + l15][k0];
      bf16x8 b0, b1;
      if (PRECONV) {
        b0 = *(const bf16x8*)(pw + (size_t)(t0 * 12 + kk) * 512);
        b1 = *(const bf16x8*)(pw + (size_t)((t0 + 1) * 12 + kk) * 512);
      } else {
        b0 = cvt8_frag(proj_w + (size_t)(t0 * 16 + l15) * 384 + k0);
        b1 = cvt8_frag(proj_w + (size_t)((t0 + 1) * 16 + l15) * 384 + k0);
      }
      acc[0] = mfma16(a, b0, acc[0]);
      acc[1] = mfma16(a, b1, acc[1]);
    }
#pragma unroll
    for (int jn = 0; jn < 2; ++jn) {
      const int col = nc * 64 + np * 32 + jn * 16 + l15;
      const float pb = proj_b[col];
#pragma unroll
      for (int r = 0; r < 4; ++r) {
        const int token = mb * 32 + mp * 16 + quad * 4 + r;
        out[(size_t)token * 384 + col] = acc[jn][r] + pb;
      }
    }
  }
}

extern "C" void kernel_launch(void* const* d_in, const int* in_sizes, int n_in,
                              void* d_out, int out_size, void* d_ws, size_t ws_size,
                              hipStream_t stream) {
  const float* x      = (const float*)d_in[0];
  const float* mask   = (const float*)d_in[1];
  const float* qkv_w  = (const float*)d_in[2];
  const float* qkv_b  = (const float*)d_in[3];
  const float* proj_w = (const float*)d_in[4];
  const float* proj_b = (const float*)d_in[5];
  const float* rpb    = (const float*)d_in[6];
  const float* lamb   = (const float*)d_in[7];
  float* out = (float*)d_out;

  // ws: 589824 ushort (frags) + 28812 f32 (bias table)
  const size_t conv_bytes = (size_t)589824 * 2 + (size_t)28812 * 4;
  unsigned short* wbf = (unsigned short*)d_ws;
  const float* biasws = (const float*)(wbf + 589824);

  if (ws_size >= conv_bytes) {
    conv_w_kernel<<<401, 256, 0, stream>>>(qkv_w, proj_w, rpb, wbf);
    attn_kernel<true><<<4096, 256, 0, stream>>>(x, mask, qkv_w, qkv_b, rpb, lamb,
                                                wbf, biasws, out);
    proj_kernel<true><<<6272, 256, 0, stream>>>(proj_w, proj_b, wbf + 442368, out);
  } else {
    attn_kernel<false><<<4096, 256, 0, stream>>>(x, mask, qkv_w, qkv_b, rpb, lamb,
                                                 nullptr, nullptr, out);
    proj_kernel<false><<<6272, 256, 0, stream>>>(proj_w, proj_b, nullptr, out);
  }
}